// Round 1
// baseline (1309.585 us; speedup 1.0000x reference)
//
#include <hip/hip_runtime.h>
#include <hip/hip_bf16.h>
#include <stdint.h>

// ---------------------------------------------------------------------------
// GCN encoder: direct-atomic scatter-add (segment_sum) -> relu -> GEMM1
// (978->2048) + relu -> GEMM2 (2048->100). bf16 MFMA for both GEMMs.
//
// R4: replaced the binned scatter pipeline (hist+scan+binscatter+accum,
// ~620us, 1.7GB traffic from 2M scattered ~40B pair segments) with a single
// direct global_atomic_add_f32 scatter kernel keeping R3's wins: 8-deep load
// batching, bf16 gather table (16MB), coalesced uint2 edge loads, 2048 WGs.
// agg (32MB) is L3-resident; 20M fire-and-forget f32 atomics, ~2.4 ops/addr.
// ---------------------------------------------------------------------------

typedef unsigned short u16;
typedef unsigned int u32;
typedef __bf16 bf16x8 __attribute__((ext_vector_type(8)));
typedef float f32x4 __attribute__((ext_vector_type(4)));

#define NGENES 978
#define KPAD   1024
#define H1DIM  2048
#define NOUT   100
#define NOUTP  112   // padded to 7 * 16
#define KSPLIT 8

#define NWG_SC 2048  // scatter workgroups

// round-to-nearest-even f32 -> bf16
__device__ __forceinline__ u16 f2b(float f) {
    unsigned u = __builtin_bit_cast(unsigned, f);
    u = (u + 0x7FFFu + ((u >> 16) & 1u)) >> 16;
    return (u16)u;
}

__device__ __forceinline__ float b2f(u16 v) {
    return __builtin_bit_cast(float, (u32)v << 16);
}

// async 16B global -> LDS direct copy (wave-uniform base + lane*16 layout)
__device__ __forceinline__ void gl2lds16(const void* g, void* l) {
    __builtin_amdgcn_global_load_lds(
        (const __attribute__((address_space(1))) void*)(uintptr_t)g,
        (__attribute__((address_space(3))) void*)(unsigned)(uintptr_t)l,
        16, 0, 0);
}

// ---------------------------------------------------------------------------
// Detect whether edges buffer is int64 (odd 4-byte words all zero) or int32.
// ---------------------------------------------------------------------------
__global__ void detect_kernel(const unsigned* __restrict__ e, int* __restrict__ flag) {
    if (threadIdx.x == 0) {
        int is64 = 1;
        for (int i = 0; i < 64; ++i) {
            if (e[2 * i + 1] != 0u) { is64 = 0; break; }
        }
        *flag = is64;
    }
}

// ---------------------------------------------------------------------------
// xb[n] = bf16(inputs[n] * gcn_w) — the gather table (16 MB instead of 32).
// ---------------------------------------------------------------------------
__global__ void xbf_kernel(const float* __restrict__ x, const float* __restrict__ gcn_w,
                           u16* __restrict__ xb, int N) {
    const float w = gcn_w[0];
    int i = (blockIdx.x * 256 + threadIdx.x) * 4;
    if (i + 3 < N) {
        float4 v = *(const float4*)&x[i];
        xb[i + 0] = f2b(v.x * w);
        xb[i + 1] = f2b(v.y * w);
        xb[i + 2] = f2b(v.z * w);
        xb[i + 3] = f2b(v.w * w);
    } else {
        for (int k = i; k < N; ++k) xb[k] = f2b(x[k] * w);
    }
}

// ---------------------------------------------------------------------------
// Direct-atomic scatter: agg[dst] += xb[src]. 8-deep batched loads, native
// mem-side f32 atomic add (fire-and-forget). agg must be pre-zeroed.
// ---------------------------------------------------------------------------
__global__ __launch_bounds__(256) void scatter2_kernel(const void* __restrict__ edges,
                                                       const u16* __restrict__ xb,
                                                       const int* __restrict__ flag, int E,
                                                       float* __restrict__ agg) {
    const int wg = blockIdx.x;
    const int per = (E + NWG_SC - 1) / NWG_SC;
    const int s = wg * per;
    const int e = min(E, s + per);
    int i = s + threadIdx.x;
    if (*flag) {
        const uint2* s64 = (const uint2*)edges;
        const uint2* d64 = s64 + E;
        for (; i + 7 * 256 < e; i += 8 * 256) {
            u32 src[8], d[8];
#pragma unroll
            for (int k = 0; k < 8; ++k) src[k] = s64[i + k * 256].x;
#pragma unroll
            for (int k = 0; k < 8; ++k) d[k] = d64[i + k * 256].x;
            u16 val[8];
#pragma unroll
            for (int k = 0; k < 8; ++k) val[k] = xb[src[k]];
#pragma unroll
            for (int k = 0; k < 8; ++k) unsafeAtomicAdd(&agg[d[k]], b2f(val[k]));
        }
        for (; i < e; i += 256) {
            u32 sv = s64[i].x;
            u32 d = d64[i].x;
            unsafeAtomicAdd(&agg[d], b2f(xb[sv]));
        }
    } else {
        const u32* s32 = (const u32*)edges;
        const u32* d32 = s32 + E;
        for (; i + 7 * 256 < e; i += 8 * 256) {
            u32 src[8], d[8];
#pragma unroll
            for (int k = 0; k < 8; ++k) src[k] = s32[i + k * 256];
#pragma unroll
            for (int k = 0; k < 8; ++k) d[k] = d32[i + k * 256];
            u16 val[8];
#pragma unroll
            for (int k = 0; k < 8; ++k) val[k] = xb[src[k]];
#pragma unroll
            for (int k = 0; k < 8; ++k) unsafeAtomicAdd(&agg[d[k]], b2f(val[k]));
        }
        for (; i < e; i += 256) {
            u32 sv = s32[i];
            u32 d = d32[i];
            unsafeAtomicAdd(&agg[d], b2f(xb[sv]));
        }
    }
}

// ---------------------------------------------------------------------------
// Fused bias + relu + bf16 convert, pad K 978 -> 1024 with zeros.
// ---------------------------------------------------------------------------
__global__ void act_kernel(const float* __restrict__ agg, const float* __restrict__ gcn_b,
                           u16* __restrict__ A) {
    int idx = blockIdx.x * 256 + threadIdx.x;
    int i = idx >> 10;         // KPAD = 1024
    int k = idx & 1023;
    float v = 0.f;
    if (k < NGENES) {
        v = agg[(size_t)i * NGENES + k] + gcn_b[0];
        v = v > 0.f ? v : 0.f;
    }
    A[idx] = f2b(v);
}

// ---------------------------------------------------------------------------
// W1 [978][2048] f32 -> W1T [2048][1024] bf16 (transposed, K zero-padded)
// ---------------------------------------------------------------------------
__global__ void transposeW1(const float* __restrict__ W1, u16* __restrict__ W1T) {
    __shared__ float t[32][33];
    int n0 = blockIdx.x * 32;
    int k0 = blockIdx.y * 32;
    int tx = threadIdx.x, ty = threadIdx.y;
    for (int r = ty; r < 32; r += 8) {
        int k = k0 + r;
        t[r][tx] = (k < NGENES) ? W1[(size_t)k * H1DIM + n0 + tx] : 0.f;
    }
    __syncthreads();
    for (int r = ty; r < 32; r += 8) {
        int n = n0 + r;
        W1T[(size_t)n * KPAD + k0 + tx] = f2b(t[tx][r]);
    }
}

// ---------------------------------------------------------------------------
// W2 [2048][100] f32 -> W2T [112][2048] bf16 (transposed, N zero-padded)
// ---------------------------------------------------------------------------
__global__ void transposeW2(const float* __restrict__ W2, u16* __restrict__ W2T) {
    __shared__ float t[32][33];
    int n0 = blockIdx.x * 32;
    int k0 = blockIdx.y * 32;
    int tx = threadIdx.x, ty = threadIdx.y;
    for (int r = ty; r < 32; r += 8) {
        int k = k0 + r;
        int n = n0 + tx;
        t[r][tx] = (n < NOUT) ? W2[(size_t)k * NOUT + n] : 0.f;
    }
    __syncthreads();
    for (int r = ty; r < 32; r += 8) {
        int n = n0 + r;
        if (n < NOUTP) W2T[(size_t)n * H1DIM + k0 + tx] = f2b(t[tx][r]);
    }
}

// ---------------------------------------------------------------------------
// GEMM1: H[8192][2048] = relu(A[8192][1024] @ W1T^T + b1), bf16 out.
// 128x128 tile, BK=32, 4 waves 2x2, 16x16x32 MFMA, global_load_lds width=16.
// ---------------------------------------------------------------------------
__global__ __launch_bounds__(256) void gemm1_kernel(const u16* __restrict__ A,
                                                    const u16* __restrict__ Bt,
                                                    const float* __restrict__ b1,
                                                    u16* __restrict__ H) {
    __shared__ u16 As[128 * 32];
    __shared__ u16 Bs[128 * 32];
    const int tid = threadIdx.x;
    const int m0 = blockIdx.y * 128;
    const int n0 = blockIdx.x * 128;
    const int wave = tid >> 6;
    const int lane = tid & 63;
    const int wm = (wave >> 1) * 64;
    const int wn = (wave & 1) * 64;
    const int quad = lane >> 4;
    const int l16 = lane & 15;

    f32x4 acc[4][4];
#pragma unroll
    for (int i = 0; i < 4; ++i)
#pragma unroll
        for (int j = 0; j < 4; ++j)
            acc[i][j] = (f32x4){0.f, 0.f, 0.f, 0.f};

    const int ch0 = tid, ch1 = tid + 256;
    const u16* ag0 = A + (size_t)(m0 + (ch0 >> 2)) * KPAD + (ch0 & 3) * 8;
    const u16* ag1 = A + (size_t)(m0 + (ch1 >> 2)) * KPAD + (ch1 & 3) * 8;
    const u16* bg0 = Bt + (size_t)(n0 + (ch0 >> 2)) * KPAD + (ch0 & 3) * 8;
    const u16* bg1 = Bt + (size_t)(n0 + (ch1 >> 2)) * KPAD + (ch1 & 3) * 8;
    u16* la0 = &As[ch0 * 8];
    u16* la1 = &As[ch1 * 8];
    u16* lb0 = &Bs[ch0 * 8];
    u16* lb1 = &Bs[ch1 * 8];

    for (int k0 = 0; k0 < KPAD; k0 += 32) {
        gl2lds16(ag0, la0);
        gl2lds16(ag1, la1);
        gl2lds16(bg0, lb0);
        gl2lds16(bg1, lb1);
        ag0 += 32; ag1 += 32; bg0 += 32; bg1 += 32;
        __syncthreads();

        bf16x8 af[4], bfr[4];
#pragma unroll
        for (int i = 0; i < 4; ++i)
            af[i] = *(const bf16x8*)&As[(wm + i * 16 + l16) * 32 + quad * 8];
#pragma unroll
        for (int j = 0; j < 4; ++j)
            bfr[j] = *(const bf16x8*)&Bs[(wn + j * 16 + l16) * 32 + quad * 8];
#pragma unroll
        for (int i = 0; i < 4; ++i)
#pragma unroll
            for (int j = 0; j < 4; ++j)
                acc[i][j] = __builtin_amdgcn_mfma_f32_16x16x32_bf16(af[i], bfr[j], acc[i][j], 0, 0, 0);
        __syncthreads();
    }

#pragma unroll
    for (int j = 0; j < 4; ++j) {
        const int col = n0 + wn + j * 16 + l16;
        const float bv = b1[col];
#pragma unroll
        for (int i = 0; i < 4; ++i) {
            const int rbase = m0 + wm + i * 16 + quad * 4;
#pragma unroll
            for (int r = 0; r < 4; ++r) {
                float v = acc[i][j][r] + bv;
                v = v > 0.f ? v : 0.f;
                H[(size_t)(rbase + r) * H1DIM + col] = f2b(v);
            }
        }
    }
}

// ---------------------------------------------------------------------------
// GEMM2: out[8192][100] += H[8192][2048] @ W2T^T + b2, split-K with atomics.
// ---------------------------------------------------------------------------
__global__ __launch_bounds__(256) void gemm2_kernel(const u16* __restrict__ Hh,
                                                    const u16* __restrict__ W2T,
                                                    const float* __restrict__ b2,
                                                    float* __restrict__ out) {
    __shared__ u16 As[64 * 32];
    __shared__ u16 Bs[NOUTP * 32];
    const int tid = threadIdx.x;
    const int m0 = blockIdx.y * 64;
    const int kc = blockIdx.x;
    const int kbase = kc * (H1DIM / KSPLIT);
    const int wave = tid >> 6;
    const int lane = tid & 63;
    const int quad = lane >> 4;
    const int l16 = lane & 15;

    f32x4 acc[7];
#pragma unroll
    for (int j = 0; j < 7; ++j) acc[j] = (f32x4){0.f, 0.f, 0.f, 0.f};

    const u16* ag = Hh + (size_t)(m0 + (tid >> 2)) * H1DIM + kbase + (tid & 3) * 8;
    u16* la = &As[tid * 8];
    const u16* bg0 = W2T + (size_t)(tid >> 2) * H1DIM + kbase + (tid & 3) * 8;
    u16* lb0 = &Bs[tid * 8];
    const int ch1 = tid + 256;
    const u16* bg1 = W2T + (size_t)(ch1 >> 2) * H1DIM + kbase + (ch1 & 3) * 8;
    u16* lb1 = &Bs[ch1 * 8];
    const bool bact = (ch1 < NOUTP * 4);

    for (int kk = 0; kk < H1DIM / KSPLIT; kk += 32) {
        gl2lds16(ag, la);
        gl2lds16(bg0, lb0);
        if (bact) gl2lds16(bg1, lb1);
        ag += 32; bg0 += 32; bg1 += 32;
        __syncthreads();

        bf16x8 af = *(const bf16x8*)&As[(wave * 16 + l16) * 32 + quad * 8];
#pragma unroll
        for (int j = 0; j < 7; ++j) {
            bf16x8 bfr = *(const bf16x8*)&Bs[(j * 16 + l16) * 32 + quad * 8];
            acc[j] = __builtin_amdgcn_mfma_f32_16x16x32_bf16(af, bfr, acc[j], 0, 0, 0);
        }
        __syncthreads();
    }

#pragma unroll
    for (int j = 0; j < 7; ++j) {
        const int col = j * 16 + l16;
        if (col < NOUT) {
            const float bv = (kc == 0) ? b2[col] : 0.f;
            const int rbase = m0 + wave * 16 + quad * 4;
#pragma unroll
            for (int r = 0; r < 4; ++r)
                atomicAdd(&out[(size_t)(rbase + r) * NOUT + col], acc[j][r] + bv);
        }
    }
}

// ---------------------------------------------------------------------------
extern "C" void kernel_launch(void* const* d_in, const int* in_sizes, int n_in,
                              void* d_out, int out_size, void* d_ws, size_t ws_size,
                              hipStream_t stream) {
    const float* inputs = (const float*)d_in[0];
    const void*  edges  = d_in[1];
    const float* gcn_w  = (const float*)d_in[2];
    const float* gcn_b  = (const float*)d_in[3];
    const float* W1     = (const float*)d_in[4];
    const float* b1     = (const float*)d_in[5];
    const float* W2     = (const float*)d_in[6];
    const float* b2     = (const float*)d_in[7];
    float* out = (float*)d_out;

    const int N = in_sizes[0];          // 8192 * 978 = 8,011,776
    const int Brows = N / NGENES;       // 8192
    const int E = in_sizes[1] / 2;      // 20,000,000

    char* ws = (char*)d_ws;
    size_t off = 0;
    auto carve = [&](size_t bytes) -> void* {
        void* p = ws + off;
        off = (off + bytes + 255) & ~(size_t)255;
        return p;
    };
    float* agg = (float*)carve((size_t)N * 4);
    u16*   Abf = (u16*)carve((size_t)Brows * KPAD * 2);
    u16*   W1T = (u16*)carve((size_t)H1DIM * KPAD * 2);
    u16*   W2Tp = (u16*)carve((size_t)NOUTP * H1DIM * 2);
    u16*   H1  = (u16*)carve((size_t)Brows * H1DIM * 2);
    int*   flag = (int*)carve(256);
    u16*   xb  = (u16*)carve((size_t)N * 2);

    hipMemsetAsync(out, 0, (size_t)out_size * 4, stream);
    hipMemsetAsync(agg, 0, (size_t)N * 4, stream);
    detect_kernel<<<1, 64, 0, stream>>>((const unsigned*)edges, flag);

    xbf_kernel<<<(N / 4 + 255) / 256, 256, 0, stream>>>(inputs, gcn_w, xb, N);
    scatter2_kernel<<<NWG_SC, 256, 0, stream>>>(edges, xb, flag, E, agg);

    act_kernel<<<(Brows * KPAD) / 256, 256, 0, stream>>>(agg, gcn_b, Abf);

    transposeW1<<<dim3(H1DIM / 32, KPAD / 32), dim3(32, 8), 0, stream>>>(W1, W1T);
    transposeW2<<<dim3(4, H1DIM / 32), dim3(32, 8), 0, stream>>>(W2, W2Tp);

    gemm1_kernel<<<dim3(H1DIM / 128, Brows / 128), 256, 0, stream>>>(Abf, W1T, b1, H1);
    gemm2_kernel<<<dim3(KSPLIT, Brows / 64), 256, 0, stream>>>(H1, W2Tp, b2, out);
}

// Round 2
// 1007.366 us; speedup vs baseline: 1.3000x; 1.3000x over previous
//
#include <hip/hip_runtime.h>
#include <hip/hip_bf16.h>
#include <stdint.h>

// ---------------------------------------------------------------------------
// GCN encoder: binned scatter-add (segment_sum) -> relu -> GEMM1(978->2048)
// + relu -> GEMM2(2048->100). bf16 MFMA for both GEMMs (fp32 accumulate).
//
// R5: R4's direct-atomic scatter regressed (agg 32MB >> 4MB L2/XCD: 20M
// random RMW atomics all miss L2, 992us). Reverted to R3 binned pipeline
// with the write-working-set fix: binscatter at 256 WGs x 512 thr so each
// XCD holds 32 WGs x 978 open segments x 64B = 2MB < 4MB L2 -> pairs lines
// stay resident until full (16 x 4B), killing the 5.6x write amplification.
// hist stays at 2048 chunks; each scatter WG owns 8 chunks, cursor = prefix
// at its first chunk.
// ---------------------------------------------------------------------------

typedef unsigned short u16;
typedef unsigned int u32;
typedef __bf16 bf16x8 __attribute__((ext_vector_type(8)));
typedef float f32x4 __attribute__((ext_vector_type(4)));

#define NGENES 978
#define KPAD   1024
#define H1DIM  2048
#define NOUT   100
#define NOUTP  112   // padded to 7 * 16
#define KSPLIT 8

// scatter binning: 8,011,776 nodes = 978 buckets x 8192 nodes (exact)
#define NB      978
#define BSH     13
#define BNODES  8192
#define NWG_BIN 2048    // hist chunk count (unchanged from R3)
#define SC_WGS  256     // binscatter workgroups (8 chunks each)
#define SC_THR  512     // binscatter threads per WG

// round-to-nearest-even f32 -> bf16
__device__ __forceinline__ u16 f2b(float f) {
    unsigned u = __builtin_bit_cast(unsigned, f);
    u = (u + 0x7FFFu + ((u >> 16) & 1u)) >> 16;
    return (u16)u;
}

// async 16B global -> LDS direct copy (wave-uniform base + lane*16 layout)
__device__ __forceinline__ void gl2lds16(const void* g, void* l) {
    __builtin_amdgcn_global_load_lds(
        (const __attribute__((address_space(1))) void*)(uintptr_t)g,
        (__attribute__((address_space(3))) void*)(unsigned)(uintptr_t)l,
        16, 0, 0);
}

// ---------------------------------------------------------------------------
// Detect whether edges buffer is int64 (odd 4-byte words all zero) or int32.
// ---------------------------------------------------------------------------
__global__ void detect_kernel(const unsigned* __restrict__ e, int* __restrict__ flag) {
    if (threadIdx.x == 0) {
        int is64 = 1;
        for (int i = 0; i < 64; ++i) {
            if (e[2 * i + 1] != 0u) { is64 = 0; break; }
        }
        *flag = is64;
    }
}

// ---------------------------------------------------------------------------
// xb[n] = bf16(inputs[n] * gcn_w) — the gather table (16 MB instead of 32).
// ---------------------------------------------------------------------------
__global__ void xbf_kernel(const float* __restrict__ x, const float* __restrict__ gcn_w,
                           u16* __restrict__ xb, int N) {
    const float w = gcn_w[0];
    int i = (blockIdx.x * 256 + threadIdx.x) * 4;
    if (i + 3 < N) {
        float4 v = *(const float4*)&x[i];
        xb[i + 0] = f2b(v.x * w);
        xb[i + 1] = f2b(v.y * w);
        xb[i + 2] = f2b(v.z * w);
        xb[i + 3] = f2b(v.w * w);
    } else {
        for (int k = i; k < N; ++k) xb[k] = f2b(x[k] * w);
    }
}

// ---------------------------------------------------------------------------
// Binned scatter, kernel A: per-chunk bucket histogram of dst. 8-deep batched.
// hist layout bucket-major: hist[b * NWG_BIN + wg]
// ---------------------------------------------------------------------------
__global__ __launch_bounds__(256) void hist_kernel(const void* __restrict__ edges,
                                                   const int* __restrict__ flag, int E,
                                                   u32* __restrict__ hist) {
    __shared__ u32 h[NB];
    for (int i = threadIdx.x; i < NB; i += 256) h[i] = 0;
    __syncthreads();
    const int wg = blockIdx.x;
    const int per = (E + NWG_BIN - 1) / NWG_BIN;
    const int s = wg * per;
    const int e = min(E, s + per);
    int i = s + threadIdx.x;
    if (*flag) {
        const uint2* dst64 = (const uint2*)edges + E;
        for (; i + 7 * 256 < e; i += 8 * 256) {
            u32 d[8];
#pragma unroll
            for (int k = 0; k < 8; ++k) d[k] = dst64[i + k * 256].x;
#pragma unroll
            for (int k = 0; k < 8; ++k) atomicAdd(&h[d[k] >> BSH], 1u);
        }
        for (; i < e; i += 256) atomicAdd(&h[dst64[i].x >> BSH], 1u);
    } else {
        const u32* dst32 = (const u32*)edges + E;
        for (; i + 7 * 256 < e; i += 8 * 256) {
            u32 d[8];
#pragma unroll
            for (int k = 0; k < 8; ++k) d[k] = dst32[i + k * 256];
#pragma unroll
            for (int k = 0; k < 8; ++k) atomicAdd(&h[d[k] >> BSH], 1u);
        }
        for (; i < e; i += 256) atomicAdd(&h[dst32[i] >> BSH], 1u);
    }
    __syncthreads();
    for (int b = threadIdx.x; b < NB; b += 256) hist[(size_t)b * NWG_BIN + wg] = h[b];
}

// ---------------------------------------------------------------------------
// Kernel B: per-bucket exclusive scan over the NWG_BIN chunk counts (in place)
// plus per-bucket totals. One wave per bucket.
// ---------------------------------------------------------------------------
__global__ void scan_wg_kernel(u32* __restrict__ hist, u32* __restrict__ totals) {
    const int b = blockIdx.x;
    u32* row = hist + (size_t)b * NWG_BIN;
    const int lane = threadIdx.x;
    u32 running = 0;
#pragma unroll
    for (int it = 0; it < NWG_BIN / 64; ++it) {
        u32 v = row[it * 64 + lane];
        u32 incl = v;
#pragma unroll
        for (int off = 1; off < 64; off <<= 1) {
            u32 t = __shfl_up(incl, off, 64);
            if (lane >= off) incl += t;
        }
        row[it * 64 + lane] = running + incl - v;
        running += __shfl(incl, 63, 64);
    }
    if (lane == 0) totals[b] = running;
}

// ---------------------------------------------------------------------------
// Kernel B2: exclusive scan of NB bucket totals -> bases[0..NB] (bases[NB]=E).
// ---------------------------------------------------------------------------
__global__ void scan_bucket_kernel(const u32* __restrict__ totals, u32* __restrict__ bases) {
    const int lane = threadIdx.x;
    u32 running = 0;
    const int iters = (NB + 63) / 64;
    for (int it = 0; it < iters; ++it) {
        int idx = it * 64 + lane;
        u32 v = (idx < NB) ? totals[idx] : 0;
        u32 incl = v;
#pragma unroll
        for (int off = 1; off < 64; off <<= 1) {
            u32 t = __shfl_up(incl, off, 64);
            if (lane >= off) incl += t;
        }
        if (idx < NB) bases[idx] = running + incl - v;
        running += __shfl(incl, 63, 64);
    }
    if (lane == 0) bases[NB] = running;
}

// ---------------------------------------------------------------------------
// Kernel C: scatter edges into bucket-grouped packed pairs. 8-deep batched.
// pair = (dst_local << 16) | xb[src]. LDS per-bucket cursors, deterministic
// offsets -> zero global atomics.
// R5: 256 WGs x 512 thr; each WG owns 8 consecutive hist chunks so the
// per-XCD open-segment working set (32 WGs x 978 lines) fits 4MB L2.
// ---------------------------------------------------------------------------
__global__ __launch_bounds__(SC_THR) void binscatter_kernel(const void* __restrict__ edges,
                                                            const u16* __restrict__ xb,
                                                            const int* __restrict__ flag, int E,
                                                            const u32* __restrict__ hist,
                                                            const u32* __restrict__ bases,
                                                            u32* __restrict__ pairs) {
    __shared__ u32 cur[NB];
    const int wg = blockIdx.x;
    // cursor = global bucket base + exclusive prefix at this WG's first chunk
    for (int b = threadIdx.x; b < NB; b += SC_THR)
        cur[b] = bases[b] + hist[(size_t)b * NWG_BIN + wg * (NWG_BIN / SC_WGS)];
    __syncthreads();
    const int per = (E + NWG_BIN - 1) / NWG_BIN;      // hist chunk size
    const int s = wg * (NWG_BIN / SC_WGS) * per;      // first chunk start
    const int e = min(E, s + (NWG_BIN / SC_WGS) * per);
    int i = s + threadIdx.x;
    if (*flag) {
        const uint2* e64 = (const uint2*)edges;
        const uint2* d64 = e64 + E;
        for (; i + 7 * SC_THR < e; i += 8 * SC_THR) {
            u32 src[8], d[8];
            u16 val[8];
#pragma unroll
            for (int k = 0; k < 8; ++k) src[k] = e64[i + k * SC_THR].x;
#pragma unroll
            for (int k = 0; k < 8; ++k) val[k] = xb[src[k]];
#pragma unroll
            for (int k = 0; k < 8; ++k) d[k] = d64[i + k * SC_THR].x;
#pragma unroll
            for (int k = 0; k < 8; ++k) {
                u32 pos = atomicAdd(&cur[d[k] >> BSH], 1u);
                pairs[pos] = ((d[k] & (BNODES - 1)) << 16) | (u32)val[k];
            }
        }
        for (; i < e; i += SC_THR) {
            u32 src = e64[i].x;
            u32 d = d64[i].x;
            u16 v = xb[src];
            u32 pos = atomicAdd(&cur[d >> BSH], 1u);
            pairs[pos] = ((d & (BNODES - 1)) << 16) | (u32)v;
        }
    } else {
        const u32* e32 = (const u32*)edges;
        const u32* d32 = e32 + E;
        for (; i + 7 * SC_THR < e; i += 8 * SC_THR) {
            u32 src[8], d[8];
            u16 val[8];
#pragma unroll
            for (int k = 0; k < 8; ++k) src[k] = e32[i + k * SC_THR];
#pragma unroll
            for (int k = 0; k < 8; ++k) val[k] = xb[src[k]];
#pragma unroll
            for (int k = 0; k < 8; ++k) d[k] = d32[i + k * SC_THR];
#pragma unroll
            for (int k = 0; k < 8; ++k) {
                u32 pos = atomicAdd(&cur[d[k] >> BSH], 1u);
                pairs[pos] = ((d[k] & (BNODES - 1)) << 16) | (u32)val[k];
            }
        }
        for (; i < e; i += SC_THR) {
            u32 src = e32[i];
            u32 d = d32[i];
            u16 v = xb[src];
            u32 pos = atomicAdd(&cur[d >> BSH], 1u);
            pairs[pos] = ((d & (BNODES - 1)) << 16) | (u32)v;
        }
    }
}

// ---------------------------------------------------------------------------
// Kernel D: per-bucket LDS accumulate (32KB fp32 tile), stream pairs, write agg.
// 512 threads, 4-deep batched pair reads. Covers every node -> replaces memset.
// ---------------------------------------------------------------------------
__global__ __launch_bounds__(512) void accum_kernel(const u32* __restrict__ pairs,
                                                    const u32* __restrict__ bases,
                                                    float* __restrict__ agg) {
    __shared__ float acc[BNODES];    // 32 KB
    for (int i = threadIdx.x; i < BNODES; i += 512) acc[i] = 0.f;
    __syncthreads();
    const int b = blockIdx.x;
    const u32 p0 = bases[b], p1 = bases[b + 1];
    u32 p = p0 + threadIdx.x;
    for (; p + 3 * 512 < p1; p += 4 * 512) {
        u32 pk[4];
#pragma unroll
        for (int k = 0; k < 4; ++k) pk[k] = pairs[p + k * 512];
#pragma unroll
        for (int k = 0; k < 4; ++k) {
            float v = __builtin_bit_cast(float, (pk[k] & 0xFFFFu) << 16);
            atomicAdd(&acc[pk[k] >> 16], v);
        }
    }
    for (; p < p1; p += 512) {
        u32 pk = pairs[p];
        float v = __builtin_bit_cast(float, (pk & 0xFFFFu) << 16);
        atomicAdd(&acc[pk >> 16], v);
    }
    __syncthreads();
    const size_t node0 = (size_t)b << BSH;
    for (int i = threadIdx.x; i < BNODES; i += 512) agg[node0 + i] = acc[i];
}

// ---------------------------------------------------------------------------
// Legacy direct-atomic scatter (fallback if workspace too small).
// ---------------------------------------------------------------------------
__global__ void scatter_kernel(const void* __restrict__ edges, const float* __restrict__ x,
                               const float* __restrict__ gcn_w, float* __restrict__ agg,
                               const int* __restrict__ flag, int E) {
    long long e = (long long)blockIdx.x * 256 + threadIdx.x;
    if (e >= E) return;
    int s, d;
    if (*flag) {
        const long long* e64 = (const long long*)edges;
        s = (int)e64[e];
        d = (int)e64[(long long)E + e];
    } else {
        const int* e32 = (const int*)edges;
        s = e32[e];
        d = e32[(long long)E + e];
    }
    atomicAdd(&agg[d], x[s] * gcn_w[0]);
}

// ---------------------------------------------------------------------------
// Fused bias + relu + bf16 convert, pad K 978 -> 1024 with zeros.
// ---------------------------------------------------------------------------
__global__ void act_kernel(const float* __restrict__ agg, const float* __restrict__ gcn_b,
                           u16* __restrict__ A) {
    int idx = blockIdx.x * 256 + threadIdx.x;
    int i = idx >> 10;         // KPAD = 1024
    int k = idx & 1023;
    float v = 0.f;
    if (k < NGENES) {
        v = agg[(size_t)i * NGENES + k] + gcn_b[0];
        v = v > 0.f ? v : 0.f;
    }
    A[idx] = f2b(v);
}

// ---------------------------------------------------------------------------
// W1 [978][2048] f32 -> W1T [2048][1024] bf16 (transposed, K zero-padded)
// ---------------------------------------------------------------------------
__global__ void transposeW1(const float* __restrict__ W1, u16* __restrict__ W1T) {
    __shared__ float t[32][33];
    int n0 = blockIdx.x * 32;
    int k0 = blockIdx.y * 32;
    int tx = threadIdx.x, ty = threadIdx.y;
    for (int r = ty; r < 32; r += 8) {
        int k = k0 + r;
        t[r][tx] = (k < NGENES) ? W1[(size_t)k * H1DIM + n0 + tx] : 0.f;
    }
    __syncthreads();
    for (int r = ty; r < 32; r += 8) {
        int n = n0 + r;
        W1T[(size_t)n * KPAD + k0 + tx] = f2b(t[tx][r]);
    }
}

// ---------------------------------------------------------------------------
// W2 [2048][100] f32 -> W2T [112][2048] bf16 (transposed, N zero-padded)
// ---------------------------------------------------------------------------
__global__ void transposeW2(const float* __restrict__ W2, u16* __restrict__ W2T) {
    __shared__ float t[32][33];
    int n0 = blockIdx.x * 32;
    int k0 = blockIdx.y * 32;
    int tx = threadIdx.x, ty = threadIdx.y;
    for (int r = ty; r < 32; r += 8) {
        int k = k0 + r;
        int n = n0 + tx;
        t[r][tx] = (n < NOUT) ? W2[(size_t)k * NOUT + n] : 0.f;
    }
    __syncthreads();
    for (int r = ty; r < 32; r += 8) {
        int n = n0 + r;
        if (n < NOUTP) W2T[(size_t)n * H1DIM + k0 + tx] = f2b(t[tx][r]);
    }
}

// ---------------------------------------------------------------------------
// GEMM1: H[8192][2048] = relu(A[8192][1024] @ W1T^T + b1), bf16 out.
// 128x128 tile, BK=32, 4 waves 2x2, 16x16x32 MFMA, global_load_lds width=16.
// ---------------------------------------------------------------------------
__global__ __launch_bounds__(256) void gemm1_kernel(const u16* __restrict__ A,
                                                    const u16* __restrict__ Bt,
                                                    const float* __restrict__ b1,
                                                    u16* __restrict__ H) {
    __shared__ u16 As[128 * 32];
    __shared__ u16 Bs[128 * 32];
    const int tid = threadIdx.x;
    const int m0 = blockIdx.y * 128;
    const int n0 = blockIdx.x * 128;
    const int wave = tid >> 6;
    const int lane = tid & 63;
    const int wm = (wave >> 1) * 64;
    const int wn = (wave & 1) * 64;
    const int quad = lane >> 4;
    const int l16 = lane & 15;

    f32x4 acc[4][4];
#pragma unroll
    for (int i = 0; i < 4; ++i)
#pragma unroll
        for (int j = 0; j < 4; ++j)
            acc[i][j] = (f32x4){0.f, 0.f, 0.f, 0.f};

    const int ch0 = tid, ch1 = tid + 256;
    const u16* ag0 = A + (size_t)(m0 + (ch0 >> 2)) * KPAD + (ch0 & 3) * 8;
    const u16* ag1 = A + (size_t)(m0 + (ch1 >> 2)) * KPAD + (ch1 & 3) * 8;
    const u16* bg0 = Bt + (size_t)(n0 + (ch0 >> 2)) * KPAD + (ch0 & 3) * 8;
    const u16* bg1 = Bt + (size_t)(n0 + (ch1 >> 2)) * KPAD + (ch1 & 3) * 8;
    u16* la0 = &As[ch0 * 8];
    u16* la1 = &As[ch1 * 8];
    u16* lb0 = &Bs[ch0 * 8];
    u16* lb1 = &Bs[ch1 * 8];

    for (int k0 = 0; k0 < KPAD; k0 += 32) {
        gl2lds16(ag0, la0);
        gl2lds16(ag1, la1);
        gl2lds16(bg0, lb0);
        gl2lds16(bg1, lb1);
        ag0 += 32; ag1 += 32; bg0 += 32; bg1 += 32;
        __syncthreads();

        bf16x8 af[4], bfr[4];
#pragma unroll
        for (int i = 0; i < 4; ++i)
            af[i] = *(const bf16x8*)&As[(wm + i * 16 + l16) * 32 + quad * 8];
#pragma unroll
        for (int j = 0; j < 4; ++j)
            bfr[j] = *(const bf16x8*)&Bs[(wn + j * 16 + l16) * 32 + quad * 8];
#pragma unroll
        for (int i = 0; i < 4; ++i)
#pragma unroll
            for (int j = 0; j < 4; ++j)
                acc[i][j] = __builtin_amdgcn_mfma_f32_16x16x32_bf16(af[i], bfr[j], acc[i][j], 0, 0, 0);
        __syncthreads();
    }

#pragma unroll
    for (int j = 0; j < 4; ++j) {
        const int col = n0 + wn + j * 16 + l16;
        const float bv = b1[col];
#pragma unroll
        for (int i = 0; i < 4; ++i) {
            const int rbase = m0 + wm + i * 16 + quad * 4;
#pragma unroll
            for (int r = 0; r < 4; ++r) {
                float v = acc[i][j][r] + bv;
                v = v > 0.f ? v : 0.f;
                H[(size_t)(rbase + r) * H1DIM + col] = f2b(v);
            }
        }
    }
}

// ---------------------------------------------------------------------------
// GEMM2: out[8192][100] += H[8192][2048] @ W2T^T + b2, split-K with atomics.
// ---------------------------------------------------------------------------
__global__ __launch_bounds__(256) void gemm2_kernel(const u16* __restrict__ Hh,
                                                    const u16* __restrict__ W2T,
                                                    const float* __restrict__ b2,
                                                    float* __restrict__ out) {
    __shared__ u16 As[64 * 32];
    __shared__ u16 Bs[NOUTP * 32];
    const int tid = threadIdx.x;
    const int m0 = blockIdx.y * 64;
    const int kc = blockIdx.x;
    const int kbase = kc * (H1DIM / KSPLIT);
    const int wave = tid >> 6;
    const int lane = tid & 63;
    const int quad = lane >> 4;
    const int l16 = lane & 15;

    f32x4 acc[7];
#pragma unroll
    for (int j = 0; j < 7; ++j) acc[j] = (f32x4){0.f, 0.f, 0.f, 0.f};

    const u16* ag = Hh + (size_t)(m0 + (tid >> 2)) * H1DIM + kbase + (tid & 3) * 8;
    u16* la = &As[tid * 8];
    const u16* bg0 = W2T + (size_t)(tid >> 2) * H1DIM + kbase + (tid & 3) * 8;
    u16* lb0 = &Bs[tid * 8];
    const int ch1 = tid + 256;
    const u16* bg1 = W2T + (size_t)(ch1 >> 2) * H1DIM + kbase + (ch1 & 3) * 8;
    u16* lb1 = &Bs[ch1 * 8];
    const bool bact = (ch1 < NOUTP * 4);

    for (int kk = 0; kk < H1DIM / KSPLIT; kk += 32) {
        gl2lds16(ag, la);
        gl2lds16(bg0, lb0);
        if (bact) gl2lds16(bg1, lb1);
        ag += 32; bg0 += 32; bg1 += 32;
        __syncthreads();

        bf16x8 af = *(const bf16x8*)&As[(wave * 16 + l16) * 32 + quad * 8];
#pragma unroll
        for (int j = 0; j < 7; ++j) {
            bf16x8 bfr = *(const bf16x8*)&Bs[(j * 16 + l16) * 32 + quad * 8];
            acc[j] = __builtin_amdgcn_mfma_f32_16x16x32_bf16(af, bfr, acc[j], 0, 0, 0);
        }
        __syncthreads();
    }

#pragma unroll
    for (int j = 0; j < 7; ++j) {
        const int col = j * 16 + l16;
        if (col < NOUT) {
            const float bv = (kc == 0) ? b2[col] : 0.f;
            const int rbase = m0 + wave * 16 + quad * 4;
#pragma unroll
            for (int r = 0; r < 4; ++r)
                atomicAdd(&out[(size_t)(rbase + r) * NOUT + col], acc[j][r] + bv);
        }
    }
}

// ---------------------------------------------------------------------------
extern "C" void kernel_launch(void* const* d_in, const int* in_sizes, int n_in,
                              void* d_out, int out_size, void* d_ws, size_t ws_size,
                              hipStream_t stream) {
    const float* inputs = (const float*)d_in[0];
    const void*  edges  = d_in[1];
    const float* gcn_w  = (const float*)d_in[2];
    const float* gcn_b  = (const float*)d_in[3];
    const float* W1     = (const float*)d_in[4];
    const float* b1     = (const float*)d_in[5];
    const float* W2     = (const float*)d_in[6];
    const float* b2     = (const float*)d_in[7];
    float* out = (float*)d_out;

    const int N = in_sizes[0];          // 8192 * 978 = 8,011,776
    const int Brows = N / NGENES;       // 8192
    const int E = in_sizes[1] / 2;      // 20,000,000

    char* ws = (char*)d_ws;
    size_t off = 0;
    auto carve = [&](size_t bytes) -> void* {
        void* p = ws + off;
        off = (off + bytes + 255) & ~(size_t)255;
        return p;
    };
    float* agg = (float*)carve((size_t)N * 4);
    u16*   Abf = (u16*)carve((size_t)Brows * KPAD * 2);
    u16*   W1T = (u16*)carve((size_t)H1DIM * KPAD * 2);
    u16*   W2Tp = (u16*)carve((size_t)NOUTP * H1DIM * 2);
    u16*   H1  = (u16*)carve((size_t)Brows * H1DIM * 2);
    int*   flag = (int*)carve(256);
    // binned-scatter extras
    u16*   xb     = (u16*)carve((size_t)N * 2);
    u32*   hist   = (u32*)carve((size_t)NB * NWG_BIN * 4);
    u32*   totals = (u32*)carve((size_t)NB * 4);
    u32*   bases  = (u32*)carve((size_t)(NB + 1) * 4);
    u32*   pairs  = (u32*)carve((size_t)E * 4);
    const bool use_binned = (off <= ws_size);

    hipMemsetAsync(out, 0, (size_t)out_size * 4, stream);
    detect_kernel<<<1, 64, 0, stream>>>((const unsigned*)edges, flag);

    if (use_binned) {
        xbf_kernel<<<(N / 4 + 255) / 256, 256, 0, stream>>>(inputs, gcn_w, xb, N);
        hist_kernel<<<NWG_BIN, 256, 0, stream>>>(edges, flag, E, hist);
        scan_wg_kernel<<<NB, 64, 0, stream>>>(hist, totals);
        scan_bucket_kernel<<<1, 64, 0, stream>>>(totals, bases);
        binscatter_kernel<<<SC_WGS, SC_THR, 0, stream>>>(edges, xb, flag, E,
                                                         hist, bases, pairs);
        accum_kernel<<<NB, 512, 0, stream>>>(pairs, bases, agg);
    } else {
        hipMemsetAsync(agg, 0, (size_t)N * 4, stream);
        const int sblocks = (E + 255) / 256;
        scatter_kernel<<<sblocks, 256, 0, stream>>>(edges, inputs, gcn_w, agg, flag, E);
    }

    act_kernel<<<(Brows * KPAD) / 256, 256, 0, stream>>>(agg, gcn_b, Abf);

    transposeW1<<<dim3(H1DIM / 32, KPAD / 32), dim3(32, 8), 0, stream>>>(W1, W1T);
    transposeW2<<<dim3(4, H1DIM / 32), dim3(32, 8), 0, stream>>>(W2, W2Tp);

    gemm1_kernel<<<dim3(H1DIM / 128, Brows / 128), 256, 0, stream>>>(Abf, W1T, b1, H1);
    gemm2_kernel<<<dim3(KSPLIT, Brows / 64), 256, 0, stream>>>(H1, W2Tp, b2, out);
}

// Round 3
// 883.601 us; speedup vs baseline: 1.4821x; 1.1401x over previous
//
#include <hip/hip_runtime.h>
#include <hip/hip_bf16.h>
#include <stdint.h>

// ---------------------------------------------------------------------------
// GCN encoder: binned scatter-add (segment_sum) -> relu -> GEMM1(978->2048)
// + relu -> GEMM2(2048->100). bf16 MFMA for both GEMMs (fp32 accumulate).
//
// R6: R5 post-mortem showed write amp (5.5x) comes from L2 churn evicting
// partial pairs lines (model: exp(-fills/lines) survival matches measured),
// not from working-set size. Fix A: LDS-staged full-line pairs writes --
// stage[978][32] in LDS, flush complete 16-pair (64B) groups as uint4 bursts
// to 16-aligned regions (hist counts padded to x16, pad slots are zero-pairs
// that add 0.0 to node 0). Fix B: non-temporal loads on all pure streams
// (edges, pairs, agg readback) so the xb gather table owns L2.
// ---------------------------------------------------------------------------

typedef unsigned short u16;
typedef unsigned int u32;
typedef __bf16 bf16x8 __attribute__((ext_vector_type(8)));
typedef float f32x4 __attribute__((ext_vector_type(4)));

#define NGENES 978
#define KPAD   1024
#define H1DIM  2048
#define NOUT   100
#define NOUTP  112   // padded to 7 * 16
#define KSPLIT 8

// scatter binning: 8,011,776 nodes = 978 buckets x 8192 nodes (exact)
#define NB      978
#define BSH     13
#define BNODES  8192
#define NWG_BIN 2048    // hist chunk count
#define SC_WGS  256     // binscatter workgroups (8 chunks each)
#define SC_THR  512     // binscatter threads per WG
#define SDEPTH  32      // LDS stage depth per bucket (u32 pairs)
#define OVFCAP  256     // LDS overflow ring capacity

// round-to-nearest-even f32 -> bf16
__device__ __forceinline__ u16 f2b(float f) {
    unsigned u = __builtin_bit_cast(unsigned, f);
    u = (u + 0x7FFFu + ((u >> 16) & 1u)) >> 16;
    return (u16)u;
}

__device__ __forceinline__ u32 nt_u32(const u32* p) {
    return __builtin_nontemporal_load(p);
}
__device__ __forceinline__ float nt_f32(const float* p) {
    return __builtin_nontemporal_load(p);
}

// async 16B global -> LDS direct copy (wave-uniform base + lane*16 layout)
__device__ __forceinline__ void gl2lds16(const void* g, void* l) {
    __builtin_amdgcn_global_load_lds(
        (const __attribute__((address_space(1))) void*)(uintptr_t)g,
        (__attribute__((address_space(3))) void*)(unsigned)(uintptr_t)l,
        16, 0, 0);
}

// ---------------------------------------------------------------------------
// Detect whether edges buffer is int64 (odd 4-byte words all zero) or int32.
// ---------------------------------------------------------------------------
__global__ void detect_kernel(const unsigned* __restrict__ e, int* __restrict__ flag) {
    if (threadIdx.x == 0) {
        int is64 = 1;
        for (int i = 0; i < 64; ++i) {
            if (e[2 * i + 1] != 0u) { is64 = 0; break; }
        }
        *flag = is64;
    }
}

// ---------------------------------------------------------------------------
// xb[n] = bf16(inputs[n] * gcn_w) — the gather table (16 MB instead of 32).
// ---------------------------------------------------------------------------
__global__ void xbf_kernel(const float* __restrict__ x, const float* __restrict__ gcn_w,
                           u16* __restrict__ xb, int N) {
    const float w = gcn_w[0];
    int i = (blockIdx.x * 256 + threadIdx.x) * 4;
    if (i + 3 < N) {
        float4 v = *(const float4*)&x[i];
        xb[i + 0] = f2b(v.x * w);
        xb[i + 1] = f2b(v.y * w);
        xb[i + 2] = f2b(v.z * w);
        xb[i + 3] = f2b(v.w * w);
    } else {
        for (int k = i; k < N; ++k) xb[k] = f2b(x[k] * w);
    }
}

// ---------------------------------------------------------------------------
// Binned scatter, kernel A: per-chunk bucket histogram of dst. 8-deep batched,
// non-temporal dst reads (low words only). hist[b * NWG_BIN + wg].
// ---------------------------------------------------------------------------
__global__ __launch_bounds__(256) void hist_kernel(const void* __restrict__ edges,
                                                   const int* __restrict__ flag, int E,
                                                   u32* __restrict__ hist) {
    __shared__ u32 h[NB];
    for (int i = threadIdx.x; i < NB; i += 256) h[i] = 0;
    __syncthreads();
    const int wg = blockIdx.x;
    const int per = (E + NWG_BIN - 1) / NWG_BIN;
    const int s = wg * per;
    const int e = min(E, s + per);
    const u32* eb = (const u32*)edges;
    const int st = (*flag) ? 2 : 1;                 // stride in u32 words
    const u32* dp = eb + (size_t)st * E;            // dst low words at dp[st*i]
    int i = s + threadIdx.x;
    for (; i + 7 * 256 < e; i += 8 * 256) {
        u32 d[8];
#pragma unroll
        for (int k = 0; k < 8; ++k) d[k] = nt_u32(&dp[(size_t)st * (i + k * 256)]);
#pragma unroll
        for (int k = 0; k < 8; ++k) atomicAdd(&h[d[k] >> BSH], 1u);
    }
    for (; i < e; i += 256) atomicAdd(&h[nt_u32(&dp[(size_t)st * i]) >> BSH], 1u);
    __syncthreads();
    for (int b = threadIdx.x; b < NB; b += 256) hist[(size_t)b * NWG_BIN + wg] = h[b];
}

// ---------------------------------------------------------------------------
// Kernel B: per-bucket exclusive scan over the NWG_BIN chunk counts, PADDED
// to multiples of 16 (so every (bucket,chunk-group) pairs region is 64B-
// aligned). In-place prefix + per-bucket padded totals. One wave per bucket.
// ---------------------------------------------------------------------------
__global__ void scan_wg_kernel(u32* __restrict__ hist, u32* __restrict__ totals) {
    const int b = blockIdx.x;
    u32* row = hist + (size_t)b * NWG_BIN;
    const int lane = threadIdx.x;
    u32 running = 0;
#pragma unroll
    for (int it = 0; it < NWG_BIN / 64; ++it) {
        u32 raw = row[it * 64 + lane];
        u32 v = (raw + 15u) & ~15u;      // pad each chunk count to x16
        u32 incl = v;
#pragma unroll
        for (int off = 1; off < 64; off <<= 1) {
            u32 t = __shfl_up(incl, off, 64);
            if (lane >= off) incl += t;
        }
        row[it * 64 + lane] = running + incl - v;
        running += __shfl(incl, 63, 64);
    }
    if (lane == 0) totals[b] = running;
}

// ---------------------------------------------------------------------------
// Kernel B2: exclusive scan of NB (padded) bucket totals -> bases[0..NB].
// ---------------------------------------------------------------------------
__global__ void scan_bucket_kernel(const u32* __restrict__ totals, u32* __restrict__ bases) {
    const int lane = threadIdx.x;
    u32 running = 0;
    const int iters = (NB + 63) / 64;
    for (int it = 0; it < iters; ++it) {
        int idx = it * 64 + lane;
        u32 v = (idx < NB) ? totals[idx] : 0;
        u32 incl = v;
#pragma unroll
        for (int off = 1; off < 64; off <<= 1) {
            u32 t = __shfl_up(incl, off, 64);
            if (lane >= off) incl += t;
        }
        if (idx < NB) bases[idx] = running + incl - v;
        running += __shfl(incl, 63, 64);
    }
    if (lane == 0) bases[NB] = running;
}

// ---------------------------------------------------------------------------
// Kernel C: scatter edges into bucket-grouped packed pairs via LDS line
// staging. pair = (dst_local << 16) | xb[src]. Per batch of 2048 edges:
// scatter into stage[bucket][slot], then flush complete 16-pair groups as
// 64B-aligned uint4 bursts. Regions padded to x16; pad slots written as 0
// (adds 0.0 to node 0 of the bucket). Overflow ring guards SDEPTH.
// ---------------------------------------------------------------------------
__global__ __launch_bounds__(SC_THR) void binscatter_kernel(const void* __restrict__ edges,
                                                            const u16* __restrict__ xb,
                                                            const int* __restrict__ flag, int E,
                                                            const u32* __restrict__ hist,
                                                            const u32* __restrict__ bases,
                                                            u32* __restrict__ pairs) {
    __shared__ u32 cur[NB];                 // global write position (x16 aligned)
    __shared__ u32 sfill[NB];               // staged-but-unflushed count
    __shared__ u32 stage[NB * SDEPTH];      // 125 KB
    __shared__ u32 ovf[OVFCAP * 2];         // overflow ring: (bucket, pair)
    __shared__ u32 ocount;
    const int tid = threadIdx.x;
    const int wg = blockIdx.x;
    for (int b = tid; b < NB; b += SC_THR) {
        cur[b] = bases[b] + hist[(size_t)b * NWG_BIN + wg * (NWG_BIN / SC_WGS)];
        sfill[b] = 0;
    }
    if (tid == 0) ocount = 0;
    __syncthreads();

    const int per = (E + NWG_BIN - 1) / NWG_BIN;      // hist chunk size
    const int s = wg * (NWG_BIN / SC_WGS) * per;
    const int e = min(E, s + (NWG_BIN / SC_WGS) * per);
    const u32* eb = (const u32*)edges;
    const int st = (*flag) ? 2 : 1;
    const u32* sp = eb;                               // src low words
    const u32* dp = eb + (size_t)st * E;              // dst low words

    for (int base_i = s; base_i < e; base_i += 8 * SC_THR) {
        const int idx = base_i + tid;
        u32 srcv[8], dv[8];
        u16 val[8];
#pragma unroll
        for (int k = 0; k < 8; ++k) {
            int i = idx + k * SC_THR;
            bool ok = i < e;
            srcv[k] = ok ? nt_u32(&sp[(size_t)st * i]) : 0u;
            dv[k]   = ok ? nt_u32(&dp[(size_t)st * i]) : 0xFFFFFFFFu;
        }
#pragma unroll
        for (int k = 0; k < 8; ++k)
            val[k] = (dv[k] != 0xFFFFFFFFu) ? xb[srcv[k]] : (u16)0;

#pragma unroll
        for (int h = 0; h < 2; ++h) {
            // scatter 4 edges/thread into LDS stage
#pragma unroll
            for (int k = 4 * h; k < 4 * h + 4; ++k) {
                if (dv[k] != 0xFFFFFFFFu) {
                    u32 b = dv[k] >> BSH;
                    u32 pr = ((dv[k] & (BNODES - 1)) << 16) | (u32)val[k];
                    u32 slot = atomicAdd(&sfill[b], 1u);
                    if (slot < SDEPTH) {
                        stage[b * SDEPTH + slot] = pr;
                    } else {
                        atomicSub(&sfill[b], 1u);
                        u32 o = atomicAdd(&ocount, 1u);
                        if (o < OVFCAP) { ovf[o * 2] = b; ovf[o * 2 + 1] = pr; }
                    }
                }
            }
            __syncthreads();
            // flush complete 64B groups
            for (int b = tid; b < NB; b += SC_THR) {
                u32 f = sfill[b];
                u32 nl = f >> 4;
                if (nl) {
                    u32 wbase = cur[b];
                    u32 n16 = nl << 4;
                    for (u32 j = 0; j < n16; j += 4)
                        *(uint4*)&pairs[wbase + j] = *(const uint4*)&stage[b * SDEPTH + j];
                    u32 rem = f & 15u;
                    for (u32 r = 0; r < rem; ++r)
                        stage[b * SDEPTH + r] = stage[b * SDEPTH + n16 + r];
                    cur[b] = wbase + n16;
                    sfill[b] = rem;
                }
            }
            __syncthreads();
            // re-insert overflow entries (rare path; oc is WG-uniform)
            u32 oc = ocount;
            if (oc) {
                if (tid < oc && tid < OVFCAP) {
                    u32 b = ovf[tid * 2];
                    u32 pr = ovf[tid * 2 + 1];
                    u32 slot = atomicAdd(&sfill[b], 1u);
                    stage[b * SDEPTH + slot] = pr;   // room guaranteed (fill<=15+oc)
                }
                __syncthreads();
                if (tid == 0) ocount = 0;
                __syncthreads();
            }
        }
    }
    // tail flush: write remaining pairs + zero-pad to the x16 region boundary
    for (int b = tid; b < NB; b += SC_THR) {
        u32 f = sfill[b];
        if (f) {
            u32 wbase = cur[b];
            u32 padded = (f + 15u) & ~15u;
            for (u32 j = 0; j < padded; j += 4) {
                uint4 v;
                v.x = (j + 0 < f) ? stage[b * SDEPTH + j + 0] : 0u;
                v.y = (j + 1 < f) ? stage[b * SDEPTH + j + 1] : 0u;
                v.z = (j + 2 < f) ? stage[b * SDEPTH + j + 2] : 0u;
                v.w = (j + 3 < f) ? stage[b * SDEPTH + j + 3] : 0u;
                *(uint4*)&pairs[wbase + j] = v;
            }
        }
    }
}

// ---------------------------------------------------------------------------
// Kernel D: per-bucket LDS accumulate (32KB fp32 tile), stream pairs (nt),
// write agg. Pad zero-pairs add 0.0 to node 0 — harmless.
// ---------------------------------------------------------------------------
__global__ __launch_bounds__(512) void accum_kernel(const u32* __restrict__ pairs,
                                                    const u32* __restrict__ bases,
                                                    float* __restrict__ agg) {
    __shared__ float acc[BNODES];    // 32 KB
    for (int i = threadIdx.x; i < BNODES; i += 512) acc[i] = 0.f;
    __syncthreads();
    const int b = blockIdx.x;
    const u32 p0 = bases[b], p1 = bases[b + 1];
    u32 p = p0 + threadIdx.x;
    for (; p + 3 * 512 < p1; p += 4 * 512) {
        u32 pk[4];
#pragma unroll
        for (int k = 0; k < 4; ++k) pk[k] = nt_u32(&pairs[p + k * 512]);
#pragma unroll
        for (int k = 0; k < 4; ++k) {
            float v = __builtin_bit_cast(float, (pk[k] & 0xFFFFu) << 16);
            atomicAdd(&acc[pk[k] >> 16], v);
        }
    }
    for (; p < p1; p += 512) {
        u32 pk = nt_u32(&pairs[p]);
        float v = __builtin_bit_cast(float, (pk & 0xFFFFu) << 16);
        atomicAdd(&acc[pk >> 16], v);
    }
    __syncthreads();
    const size_t node0 = (size_t)b << BSH;
    for (int i = threadIdx.x; i < BNODES; i += 512) agg[node0 + i] = acc[i];
}

// ---------------------------------------------------------------------------
// Legacy direct-atomic scatter (fallback if workspace too small).
// ---------------------------------------------------------------------------
__global__ void scatter_kernel(const void* __restrict__ edges, const float* __restrict__ x,
                               const float* __restrict__ gcn_w, float* __restrict__ agg,
                               const int* __restrict__ flag, int E) {
    long long e = (long long)blockIdx.x * 256 + threadIdx.x;
    if (e >= E) return;
    int s, d;
    if (*flag) {
        const long long* e64 = (const long long*)edges;
        s = (int)e64[e];
        d = (int)e64[(long long)E + e];
    } else {
        const int* e32 = (const int*)edges;
        s = e32[e];
        d = e32[(long long)E + e];
    }
    atomicAdd(&agg[d], x[s] * gcn_w[0]);
}

// ---------------------------------------------------------------------------
// Fused bias + relu + bf16 convert, pad K 978 -> 1024 with zeros.
// agg read is nt to protect freshly-written Abf lines for gemm1.
// ---------------------------------------------------------------------------
__global__ void act_kernel(const float* __restrict__ agg, const float* __restrict__ gcn_b,
                           u16* __restrict__ A) {
    int idx = blockIdx.x * 256 + threadIdx.x;
    int i = idx >> 10;         // KPAD = 1024
    int k = idx & 1023;
    float v = 0.f;
    if (k < NGENES) {
        v = nt_f32(&agg[(size_t)i * NGENES + k]) + gcn_b[0];
        v = v > 0.f ? v : 0.f;
    }
    A[idx] = f2b(v);
}

// ---------------------------------------------------------------------------
// W1 [978][2048] f32 -> W1T [2048][1024] bf16 (transposed, K zero-padded)
// ---------------------------------------------------------------------------
__global__ void transposeW1(const float* __restrict__ W1, u16* __restrict__ W1T) {
    __shared__ float t[32][33];
    int n0 = blockIdx.x * 32;
    int k0 = blockIdx.y * 32;
    int tx = threadIdx.x, ty = threadIdx.y;
    for (int r = ty; r < 32; r += 8) {
        int k = k0 + r;
        t[r][tx] = (k < NGENES) ? W1[(size_t)k * H1DIM + n0 + tx] : 0.f;
    }
    __syncthreads();
    for (int r = ty; r < 32; r += 8) {
        int n = n0 + r;
        W1T[(size_t)n * KPAD + k0 + tx] = f2b(t[tx][r]);
    }
}

// ---------------------------------------------------------------------------
// W2 [2048][100] f32 -> W2T [112][2048] bf16 (transposed, N zero-padded)
// ---------------------------------------------------------------------------
__global__ void transposeW2(const float* __restrict__ W2, u16* __restrict__ W2T) {
    __shared__ float t[32][33];
    int n0 = blockIdx.x * 32;
    int k0 = blockIdx.y * 32;
    int tx = threadIdx.x, ty = threadIdx.y;
    for (int r = ty; r < 32; r += 8) {
        int k = k0 + r;
        int n = n0 + tx;
        t[r][tx] = (n < NOUT) ? W2[(size_t)k * NOUT + n] : 0.f;
    }
    __syncthreads();
    for (int r = ty; r < 32; r += 8) {
        int n = n0 + r;
        if (n < NOUTP) W2T[(size_t)n * H1DIM + k0 + tx] = f2b(t[tx][r]);
    }
}

// ---------------------------------------------------------------------------
// GEMM1: H[8192][2048] = relu(A[8192][1024] @ W1T^T + b1), bf16 out.
// 128x128 tile, BK=32, 4 waves 2x2, 16x16x32 MFMA, global_load_lds width=16.
// ---------------------------------------------------------------------------
__global__ __launch_bounds__(256) void gemm1_kernel(const u16* __restrict__ A,
                                                    const u16* __restrict__ Bt,
                                                    const float* __restrict__ b1,
                                                    u16* __restrict__ H) {
    __shared__ u16 As[128 * 32];
    __shared__ u16 Bs[128 * 32];
    const int tid = threadIdx.x;
    const int m0 = blockIdx.y * 128;
    const int n0 = blockIdx.x * 128;
    const int wave = tid >> 6;
    const int lane = tid & 63;
    const int wm = (wave >> 1) * 64;
    const int wn = (wave & 1) * 64;
    const int quad = lane >> 4;
    const int l16 = lane & 15;

    f32x4 acc[4][4];
#pragma unroll
    for (int i = 0; i < 4; ++i)
#pragma unroll
        for (int j = 0; j < 4; ++j)
            acc[i][j] = (f32x4){0.f, 0.f, 0.f, 0.f};

    const int ch0 = tid, ch1 = tid + 256;
    const u16* ag0 = A + (size_t)(m0 + (ch0 >> 2)) * KPAD + (ch0 & 3) * 8;
    const u16* ag1 = A + (size_t)(m0 + (ch1 >> 2)) * KPAD + (ch1 & 3) * 8;
    const u16* bg0 = Bt + (size_t)(n0 + (ch0 >> 2)) * KPAD + (ch0 & 3) * 8;
    const u16* bg1 = Bt + (size_t)(n0 + (ch1 >> 2)) * KPAD + (ch1 & 3) * 8;
    u16* la0 = &As[ch0 * 8];
    u16* la1 = &As[ch1 * 8];
    u16* lb0 = &Bs[ch0 * 8];
    u16* lb1 = &Bs[ch1 * 8];

    for (int k0 = 0; k0 < KPAD; k0 += 32) {
        gl2lds16(ag0, la0);
        gl2lds16(ag1, la1);
        gl2lds16(bg0, lb0);
        gl2lds16(bg1, lb1);
        ag0 += 32; ag1 += 32; bg0 += 32; bg1 += 32;
        __syncthreads();

        bf16x8 af[4], bfr[4];
#pragma unroll
        for (int i = 0; i < 4; ++i)
            af[i] = *(const bf16x8*)&As[(wm + i * 16 + l16) * 32 + quad * 8];
#pragma unroll
        for (int j = 0; j < 4; ++j)
            bfr[j] = *(const bf16x8*)&Bs[(wn + j * 16 + l16) * 32 + quad * 8];
#pragma unroll
        for (int i = 0; i < 4; ++i)
#pragma unroll
            for (int j = 0; j < 4; ++j)
                acc[i][j] = __builtin_amdgcn_mfma_f32_16x16x32_bf16(af[i], bfr[j], acc[i][j], 0, 0, 0);
        __syncthreads();
    }

#pragma unroll
    for (int j = 0; j < 4; ++j) {
        const int col = n0 + wn + j * 16 + l16;
        const float bv = b1[col];
#pragma unroll
        for (int i = 0; i < 4; ++i) {
            const int rbase = m0 + wm + i * 16 + quad * 4;
#pragma unroll
            for (int r = 0; r < 4; ++r) {
                float v = acc[i][j][r] + bv;
                v = v > 0.f ? v : 0.f;
                H[(size_t)(rbase + r) * H1DIM + col] = f2b(v);
            }
        }
    }
}

// ---------------------------------------------------------------------------
// GEMM2: out[8192][100] += H[8192][2048] @ W2T^T + b2, split-K with atomics.
// ---------------------------------------------------------------------------
__global__ __launch_bounds__(256) void gemm2_kernel(const u16* __restrict__ Hh,
                                                    const u16* __restrict__ W2T,
                                                    const float* __restrict__ b2,
                                                    float* __restrict__ out) {
    __shared__ u16 As[64 * 32];
    __shared__ u16 Bs[NOUTP * 32];
    const int tid = threadIdx.x;
    const int m0 = blockIdx.y * 64;
    const int kc = blockIdx.x;
    const int kbase = kc * (H1DIM / KSPLIT);
    const int wave = tid >> 6;
    const int lane = tid & 63;
    const int quad = lane >> 4;
    const int l16 = lane & 15;

    f32x4 acc[7];
#pragma unroll
    for (int j = 0; j < 7; ++j) acc[j] = (f32x4){0.f, 0.f, 0.f, 0.f};

    const u16* ag = Hh + (size_t)(m0 + (tid >> 2)) * H1DIM + kbase + (tid & 3) * 8;
    u16* la = &As[tid * 8];
    const u16* bg0 = W2T + (size_t)(tid >> 2) * H1DIM + kbase + (tid & 3) * 8;
    u16* lb0 = &Bs[tid * 8];
    const int ch1 = tid + 256;
    const u16* bg1 = W2T + (size_t)(ch1 >> 2) * H1DIM + kbase + (ch1 & 3) * 8;
    u16* lb1 = &Bs[ch1 * 8];
    const bool bact = (ch1 < NOUTP * 4);

    for (int kk = 0; kk < H1DIM / KSPLIT; kk += 32) {
        gl2lds16(ag, la);
        gl2lds16(bg0, lb0);
        if (bact) gl2lds16(bg1, lb1);
        ag += 32; bg0 += 32; bg1 += 32;
        __syncthreads();

        bf16x8 af = *(const bf16x8*)&As[(wave * 16 + l16) * 32 + quad * 8];
#pragma unroll
        for (int j = 0; j < 7; ++j) {
            bf16x8 bfr = *(const bf16x8*)&Bs[(j * 16 + l16) * 32 + quad * 8];
            acc[j] = __builtin_amdgcn_mfma_f32_16x16x32_bf16(af, bfr, acc[j], 0, 0, 0);
        }
        __syncthreads();
    }

#pragma unroll
    for (int j = 0; j < 7; ++j) {
        const int col = j * 16 + l16;
        if (col < NOUT) {
            const float bv = (kc == 0) ? b2[col] : 0.f;
            const int rbase = m0 + wave * 16 + quad * 4;
#pragma unroll
            for (int r = 0; r < 4; ++r)
                atomicAdd(&out[(size_t)(rbase + r) * NOUT + col], acc[j][r] + bv);
        }
    }
}

// ---------------------------------------------------------------------------
extern "C" void kernel_launch(void* const* d_in, const int* in_sizes, int n_in,
                              void* d_out, int out_size, void* d_ws, size_t ws_size,
                              hipStream_t stream) {
    const float* inputs = (const float*)d_in[0];
    const void*  edges  = d_in[1];
    const float* gcn_w  = (const float*)d_in[2];
    const float* gcn_b  = (const float*)d_in[3];
    const float* W1     = (const float*)d_in[4];
    const float* b1     = (const float*)d_in[5];
    const float* W2     = (const float*)d_in[6];
    const float* b2     = (const float*)d_in[7];
    float* out = (float*)d_out;

    const int N = in_sizes[0];          // 8192 * 978 = 8,011,776
    const int Brows = N / NGENES;       // 8192
    const int E = in_sizes[1] / 2;      // 20,000,000

    char* ws = (char*)d_ws;
    size_t off = 0;
    auto carve = [&](size_t bytes) -> void* {
        void* p = ws + off;
        off = (off + bytes + 255) & ~(size_t)255;
        return p;
    };
    float* agg = (float*)carve((size_t)N * 4);
    u16*   Abf = (u16*)carve((size_t)Brows * KPAD * 2);
    u16*   W1T = (u16*)carve((size_t)H1DIM * KPAD * 2);
    u16*   W2Tp = (u16*)carve((size_t)NOUTP * H1DIM * 2);
    u16*   H1  = (u16*)carve((size_t)Brows * H1DIM * 2);
    int*   flag = (int*)carve(256);
    // binned-scatter extras
    u16*   xb     = (u16*)carve((size_t)N * 2);
    u32*   hist   = (u32*)carve((size_t)NB * NWG_BIN * 4);
    u32*   totals = (u32*)carve((size_t)NB * 4);
    u32*   bases  = (u32*)carve((size_t)(NB + 1) * 4);
    // pairs: E + padding (<=15 u32 per (bucket,chunk-group) = ~15 MB)
    u32*   pairs  = (u32*)carve((size_t)E * 4 + ((size_t)16 << 20));
    const bool use_binned = (off <= ws_size);

    hipMemsetAsync(out, 0, (size_t)out_size * 4, stream);
    detect_kernel<<<1, 64, 0, stream>>>((const unsigned*)edges, flag);

    if (use_binned) {
        xbf_kernel<<<(N / 4 + 255) / 256, 256, 0, stream>>>(inputs, gcn_w, xb, N);
        hist_kernel<<<NWG_BIN, 256, 0, stream>>>(edges, flag, E, hist);
        scan_wg_kernel<<<NB, 64, 0, stream>>>(hist, totals);
        scan_bucket_kernel<<<1, 64, 0, stream>>>(totals, bases);
        binscatter_kernel<<<SC_WGS, SC_THR, 0, stream>>>(edges, xb, flag, E,
                                                         hist, bases, pairs);
        accum_kernel<<<NB, 512, 0, stream>>>(pairs, bases, agg);
    } else {
        hipMemsetAsync(agg, 0, (size_t)N * 4, stream);
        const int sblocks = (E + 255) / 256;
        scatter_kernel<<<sblocks, 256, 0, stream>>>(edges, inputs, gcn_w, agg, flag, E);
    }

    act_kernel<<<(Brows * KPAD) / 256, 256, 0, stream>>>(agg, gcn_b, Abf);

    transposeW1<<<dim3(H1DIM / 32, KPAD / 32), dim3(32, 8), 0, stream>>>(W1, W1T);
    transposeW2<<<dim3(4, H1DIM / 32), dim3(32, 8), 0, stream>>>(W2, W2Tp);

    gemm1_kernel<<<dim3(H1DIM / 128, Brows / 128), 256, 0, stream>>>(Abf, W1T, b1, H1);
    gemm2_kernel<<<dim3(KSPLIT, Brows / 64), 256, 0, stream>>>(H1, W2Tp, b2, out);
}

// Round 4
// 786.341 us; speedup vs baseline: 1.6654x; 1.1237x over previous
//
#include <hip/hip_runtime.h>
#include <hip/hip_bf16.h>
#include <stdint.h>

// ---------------------------------------------------------------------------
// GCN encoder: binned scatter-add (segment_sum) -> relu -> GEMM1(978->2048)
// + relu -> GEMM2(2048->100). bf16 MFMA for both GEMMs (fp32 accumulate).
//
// R7: R6 proved full-line staged flushes (write amp 5.5 -> 1.08). Remaining:
// binscatter at 22% occupancy (1 WG/CU) + 8.7M LDS bank conflicts
// (stage[b*32+slot]: bank=slot%32) + hist/scan bookkeeping (160MB re-read).
// Fix: global-cursor flushes (atomicAdd 16-groups into fixed CAP=24576
// per-bucket regions; lossless spill+cleanup for overflow) delete hist/scan;
// 256 WGs x 1024 thr = 16 waves/CU; transposed stage[slot*NB+b] randomizes
// banks. Pairs lines still written whole by one thread (64B groups).
// ---------------------------------------------------------------------------

typedef unsigned short u16;
typedef unsigned int u32;
typedef __bf16 bf16x8 __attribute__((ext_vector_type(8)));
typedef float f32x4 __attribute__((ext_vector_type(4)));

#define NGENES 978
#define KPAD   1024
#define H1DIM  2048
#define NOUT   100
#define NOUTP  112   // padded to 7 * 16
#define KSPLIT 8

// scatter binning: 8,011,776 nodes = 978 buckets x 8192 nodes (exact)
#define NB      978
#define BSH     13
#define BNODES  8192
#define SC_WGS  256     // binscatter workgroups
#define SC_THR  1024    // binscatter threads per WG (16 waves/CU)
#define SDEPTH  32      // LDS stage depth per bucket (u32 pairs)
#define OVFCAP  256     // LDS overflow ring capacity
#define CAP_B   24576   // per-bucket pairs capacity (x16; mean 20450, ~9 sigma)

// round-to-nearest-even f32 -> bf16
__device__ __forceinline__ u16 f2b(float f) {
    unsigned u = __builtin_bit_cast(unsigned, f);
    u = (u + 0x7FFFu + ((u >> 16) & 1u)) >> 16;
    return (u16)u;
}

__device__ __forceinline__ u32 nt_u32(const u32* p) {
    return __builtin_nontemporal_load(p);
}
__device__ __forceinline__ float nt_f32(const float* p) {
    return __builtin_nontemporal_load(p);
}

// async 16B global -> LDS direct copy (wave-uniform base + lane*16 layout)
__device__ __forceinline__ void gl2lds16(const void* g, void* l) {
    __builtin_amdgcn_global_load_lds(
        (const __attribute__((address_space(1))) void*)(uintptr_t)g,
        (__attribute__((address_space(3))) void*)(unsigned)(uintptr_t)l,
        16, 0, 0);
}

// ---------------------------------------------------------------------------
// Detect whether edges buffer is int64 (odd 4-byte words all zero) or int32.
// ---------------------------------------------------------------------------
__global__ void detect_kernel(const unsigned* __restrict__ e, int* __restrict__ flag) {
    if (threadIdx.x == 0) {
        int is64 = 1;
        for (int i = 0; i < 64; ++i) {
            if (e[2 * i + 1] != 0u) { is64 = 0; break; }
        }
        *flag = is64;
    }
}

// ---------------------------------------------------------------------------
// xb[n] = bf16(inputs[n] * gcn_w) — the gather table (16 MB instead of 32).
// ---------------------------------------------------------------------------
__global__ void xbf_kernel(const float* __restrict__ x, const float* __restrict__ gcn_w,
                           u16* __restrict__ xb, int N) {
    const float w = gcn_w[0];
    int i = (blockIdx.x * 256 + threadIdx.x) * 4;
    if (i + 3 < N) {
        float4 v = *(const float4*)&x[i];
        xb[i + 0] = f2b(v.x * w);
        xb[i + 1] = f2b(v.y * w);
        xb[i + 2] = f2b(v.z * w);
        xb[i + 3] = f2b(v.w * w);
    } else {
        for (int k = i; k < N; ++k) xb[k] = f2b(x[k] * w);
    }
}

// ---------------------------------------------------------------------------
// Binscatter (global-cursor): scatter edges into bucket regions of pairs.
// pair = (dst_local << 16) | xb[src]. LDS stage (transposed [slot][bucket]),
// flush complete 16-pair 64B groups at positions reserved by global
// atomicAdd(cnt[b], n*16). Capacity/stage overflow spills losslessly to
// ovfg (fixed by ovf_fix_kernel after accum). No hist, no scans.
// ---------------------------------------------------------------------------
__global__ __launch_bounds__(SC_THR) void binscatter_kernel(const void* __restrict__ edges,
                                                            const u16* __restrict__ xb,
                                                            const int* __restrict__ flag, int E,
                                                            u32* __restrict__ pairs,
                                                            u32* __restrict__ cnt,
                                                            u32* __restrict__ ovfg,
                                                            u32* __restrict__ ovfcnt) {
    __shared__ u32 sfill[NB];
    __shared__ u32 stage[SDEPTH * NB];      // transposed: [slot][bucket], 125 KB
    __shared__ u32 ovf[OVFCAP * 2];         // LDS overflow ring: (bucket, pair)
    __shared__ u32 ocount;
    const int tid = threadIdx.x;
    for (int b = tid; b < NB; b += SC_THR) sfill[b] = 0;
    if (tid == 0) ocount = 0;
    __syncthreads();

    const int per = (E + SC_WGS - 1) / SC_WGS;
    const int s = blockIdx.x * per;
    const int e = min(E, s + per);
    const u32* eb = (const u32*)edges;
    const int st = (*flag) ? 2 : 1;
    const u32* sp = eb;                               // src low words
    const u32* dp = eb + (size_t)st * E;              // dst low words

    for (int base_i = s; base_i < e; base_i += 8 * SC_THR) {
        const int idx = base_i + tid;
        u32 srcv[8], dv[8];
        u16 val[8];
#pragma unroll
        for (int k = 0; k < 8; ++k) {
            int i = idx + k * SC_THR;
            bool ok = i < e;
            srcv[k] = ok ? nt_u32(&sp[(size_t)st * i]) : 0u;
            dv[k]   = ok ? nt_u32(&dp[(size_t)st * i]) : 0xFFFFFFFFu;
        }
#pragma unroll
        for (int k = 0; k < 8; ++k)
            val[k] = (dv[k] != 0xFFFFFFFFu) ? xb[srcv[k]] : (u16)0;

#pragma unroll
        for (int h = 0; h < 2; ++h) {
            // scatter 4 edges/thread into LDS stage
#pragma unroll
            for (int k = 4 * h; k < 4 * h + 4; ++k) {
                if (dv[k] != 0xFFFFFFFFu) {
                    u32 b = dv[k] >> BSH;
                    u32 pr = ((dv[k] & (BNODES - 1)) << 16) | (u32)val[k];
                    u32 slot = atomicAdd(&sfill[b], 1u);
                    if (slot < SDEPTH) {
                        stage[slot * NB + b] = pr;
                    } else {
                        atomicSub(&sfill[b], 1u);
                        u32 o = atomicAdd(&ocount, 1u);
                        if (o < OVFCAP) {
                            ovf[o * 2] = b; ovf[o * 2 + 1] = pr;
                        } else {   // lossless global spill
                            u32 og = atomicAdd(ovfcnt, 1u);
                            ovfg[og * 2] = (b << BSH) | (pr >> 16);
                            ovfg[og * 2 + 1] = pr & 0xFFFFu;
                        }
                    }
                }
            }
            __syncthreads();
            // flush complete 64B groups at globally-reserved positions
            for (int b = tid; b < NB; b += SC_THR) {
                u32 f = sfill[b];
                u32 nl = f >> 4;
                if (nl) {
                    u32 base = atomicAdd(&cnt[b], nl << 4);
                    for (u32 g = 0; g < nl; ++g) {
                        u32 wb = base + (g << 4);
                        if (wb < CAP_B) {
                            u32* dst = &pairs[(size_t)b * CAP_B + wb];
#pragma unroll
                            for (int q = 0; q < 4; ++q) {
                                uint4 v;
                                v.x = stage[(g * 16 + q * 4 + 0) * NB + b];
                                v.y = stage[(g * 16 + q * 4 + 1) * NB + b];
                                v.z = stage[(g * 16 + q * 4 + 2) * NB + b];
                                v.w = stage[(g * 16 + q * 4 + 3) * NB + b];
                                *(uint4*)&dst[q * 4] = v;
                            }
                        } else {   // capacity spill (lossless, ~never)
                            for (int q = 0; q < 16; ++q) {
                                u32 pr = stage[(g * 16 + q) * NB + b];
                                u32 og = atomicAdd(ovfcnt, 1u);
                                ovfg[og * 2] = (b << BSH) | (pr >> 16);
                                ovfg[og * 2 + 1] = pr & 0xFFFFu;
                            }
                        }
                    }
                    u32 n16 = nl << 4;
                    u32 rem = f & 15u;
                    for (u32 r = 0; r < rem; ++r)
                        stage[r * NB + b] = stage[(n16 + r) * NB + b];
                    sfill[b] = rem;
                }
            }
            __syncthreads();
            // re-insert LDS-ring overflow entries (rare; oc is WG-uniform)
            u32 oc = ocount;
            if (oc) {
                u32 m = oc < (u32)OVFCAP ? oc : (u32)OVFCAP;
                if (tid < (int)m) {
                    u32 b = ovf[tid * 2];
                    u32 pr = ovf[tid * 2 + 1];
                    u32 slot = atomicAdd(&sfill[b], 1u);
                    if (slot < SDEPTH) {
                        stage[slot * NB + b] = pr;
                    } else {
                        atomicSub(&sfill[b], 1u);
                        u32 og = atomicAdd(ovfcnt, 1u);
                        ovfg[og * 2] = (b << BSH) | (pr >> 16);
                        ovfg[og * 2 + 1] = pr & 0xFFFFu;
                    }
                }
                __syncthreads();
                if (tid == 0) ocount = 0;
                __syncthreads();
            }
        }
    }
    // tail: flush remainder, zero-padded to x16 groups
    for (int b = tid; b < NB; b += SC_THR) {
        u32 f = sfill[b];
        if (f) {
            u32 padded = (f + 15u) & ~15u;
            u32 base = atomicAdd(&cnt[b], padded);
            for (u32 g = 0; g < (padded >> 4); ++g) {
                u32 wb = base + (g << 4);
                if (wb < CAP_B) {
                    u32* dst = &pairs[(size_t)b * CAP_B + wb];
#pragma unroll
                    for (int q = 0; q < 4; ++q) {
                        uint4 v;
                        u32 j = g * 16 + q * 4;
                        v.x = (j + 0 < f) ? stage[(j + 0) * NB + b] : 0u;
                        v.y = (j + 1 < f) ? stage[(j + 1) * NB + b] : 0u;
                        v.z = (j + 2 < f) ? stage[(j + 2) * NB + b] : 0u;
                        v.w = (j + 3 < f) ? stage[(j + 3) * NB + b] : 0u;
                        *(uint4*)&dst[q * 4] = v;
                    }
                } else {
                    for (u32 q = g * 16; q < f && q < g * 16 + 16; ++q) {
                        u32 pr = stage[q * NB + b];
                        u32 og = atomicAdd(ovfcnt, 1u);
                        ovfg[og * 2] = (b << BSH) | (pr >> 16);
                        ovfg[og * 2 + 1] = pr & 0xFFFFu;
                    }
                }
            }
        }
    }
}

// ---------------------------------------------------------------------------
// Kernel D: per-bucket LDS accumulate (32KB fp32 tile), stream pairs (nt),
// write agg. Zero pad-pairs skipped. Region = [b*CAP_B, b*CAP_B+min(cnt,CAP)).
// ---------------------------------------------------------------------------
__global__ __launch_bounds__(512) void accum_kernel(const u32* __restrict__ pairs,
                                                    const u32* __restrict__ cnt,
                                                    float* __restrict__ agg) {
    __shared__ float acc[BNODES];    // 32 KB
    for (int i = threadIdx.x; i < BNODES; i += 512) acc[i] = 0.f;
    __syncthreads();
    const int b = blockIdx.x;
    u32 n = cnt[b];
    if (n > CAP_B) n = CAP_B;
    const u32 p0 = (u32)b * CAP_B;
    const u32 p1 = p0 + n;
    u32 p = p0 + threadIdx.x;
    for (; p + 3 * 512 < p1; p += 4 * 512) {
        u32 pk[4];
#pragma unroll
        for (int k = 0; k < 4; ++k) pk[k] = nt_u32(&pairs[p + k * 512]);
#pragma unroll
        for (int k = 0; k < 4; ++k) {
            if (pk[k]) {
                float v = __builtin_bit_cast(float, (pk[k] & 0xFFFFu) << 16);
                atomicAdd(&acc[pk[k] >> 16], v);
            }
        }
    }
    for (; p < p1; p += 512) {
        u32 pk = nt_u32(&pairs[p]);
        if (pk) {
            float v = __builtin_bit_cast(float, (pk & 0xFFFFu) << 16);
            atomicAdd(&acc[pk >> 16], v);
        }
    }
    __syncthreads();
    const size_t node0 = (size_t)b << BSH;
    for (int i = threadIdx.x; i < BNODES; i += 512) agg[node0 + i] = acc[i];
}

// ---------------------------------------------------------------------------
// Overflow cleanup: apply spilled (dst, val) entries to agg (after accum).
// Normally zero entries.
// ---------------------------------------------------------------------------
__global__ void ovf_fix_kernel(const u32* __restrict__ ovfg, const u32* __restrict__ ovfcnt,
                               float* __restrict__ agg) {
    u32 n = *ovfcnt;
    for (u32 i = blockIdx.x * 256 + threadIdx.x; i < n; i += gridDim.x * 256) {
        float v = __builtin_bit_cast(float, ovfg[i * 2 + 1] << 16);
        atomicAdd(&agg[ovfg[i * 2]], v);
    }
}

// ---------------------------------------------------------------------------
// Legacy direct-atomic scatter (fallback if workspace too small).
// ---------------------------------------------------------------------------
__global__ void scatter_kernel(const void* __restrict__ edges, const float* __restrict__ x,
                               const float* __restrict__ gcn_w, float* __restrict__ agg,
                               const int* __restrict__ flag, int E) {
    long long e = (long long)blockIdx.x * 256 + threadIdx.x;
    if (e >= E) return;
    int s, d;
    if (*flag) {
        const long long* e64 = (const long long*)edges;
        s = (int)e64[e];
        d = (int)e64[(long long)E + e];
    } else {
        const int* e32 = (const int*)edges;
        s = e32[e];
        d = e32[(long long)E + e];
    }
    atomicAdd(&agg[d], x[s] * gcn_w[0]);
}

// ---------------------------------------------------------------------------
// Fused bias + relu + bf16 convert, pad K 978 -> 1024 with zeros.
// ---------------------------------------------------------------------------
__global__ void act_kernel(const float* __restrict__ agg, const float* __restrict__ gcn_b,
                           u16* __restrict__ A) {
    int idx = blockIdx.x * 256 + threadIdx.x;
    int i = idx >> 10;         // KPAD = 1024
    int k = idx & 1023;
    float v = 0.f;
    if (k < NGENES) {
        v = nt_f32(&agg[(size_t)i * NGENES + k]) + gcn_b[0];
        v = v > 0.f ? v : 0.f;
    }
    A[idx] = f2b(v);
}

// ---------------------------------------------------------------------------
// W1 [978][2048] f32 -> W1T [2048][1024] bf16 (transposed, K zero-padded)
// ---------------------------------------------------------------------------
__global__ void transposeW1(const float* __restrict__ W1, u16* __restrict__ W1T) {
    __shared__ float t[32][33];
    int n0 = blockIdx.x * 32;
    int k0 = blockIdx.y * 32;
    int tx = threadIdx.x, ty = threadIdx.y;
    for (int r = ty; r < 32; r += 8) {
        int k = k0 + r;
        t[r][tx] = (k < NGENES) ? W1[(size_t)k * H1DIM + n0 + tx] : 0.f;
    }
    __syncthreads();
    for (int r = ty; r < 32; r += 8) {
        int n = n0 + r;
        W1T[(size_t)n * KPAD + k0 + tx] = f2b(t[tx][r]);
    }
}

// ---------------------------------------------------------------------------
// W2 [2048][100] f32 -> W2T [112][2048] bf16 (transposed, N zero-padded)
// ---------------------------------------------------------------------------
__global__ void transposeW2(const float* __restrict__ W2, u16* __restrict__ W2T) {
    __shared__ float t[32][33];
    int n0 = blockIdx.x * 32;
    int k0 = blockIdx.y * 32;
    int tx = threadIdx.x, ty = threadIdx.y;
    for (int r = ty; r < 32; r += 8) {
        int k = k0 + r;
        int n = n0 + tx;
        t[r][tx] = (n < NOUT) ? W2[(size_t)k * NOUT + n] : 0.f;
    }
    __syncthreads();
    for (int r = ty; r < 32; r += 8) {
        int n = n0 + r;
        if (n < NOUTP) W2T[(size_t)n * H1DIM + k0 + tx] = f2b(t[tx][r]);
    }
}

// ---------------------------------------------------------------------------
// GEMM1: H[8192][2048] = relu(A[8192][1024] @ W1T^T + b1), bf16 out.
// 128x128 tile, BK=32, 4 waves 2x2, 16x16x32 MFMA, global_load_lds width=16.
// ---------------------------------------------------------------------------
__global__ __launch_bounds__(256) void gemm1_kernel(const u16* __restrict__ A,
                                                    const u16* __restrict__ Bt,
                                                    const float* __restrict__ b1,
                                                    u16* __restrict__ H) {
    __shared__ u16 As[128 * 32];
    __shared__ u16 Bs[128 * 32];
    const int tid = threadIdx.x;
    const int m0 = blockIdx.y * 128;
    const int n0 = blockIdx.x * 128;
    const int wave = tid >> 6;
    const int lane = tid & 63;
    const int wm = (wave >> 1) * 64;
    const int wn = (wave & 1) * 64;
    const int quad = lane >> 4;
    const int l16 = lane & 15;

    f32x4 acc[4][4];
#pragma unroll
    for (int i = 0; i < 4; ++i)
#pragma unroll
        for (int j = 0; j < 4; ++j)
            acc[i][j] = (f32x4){0.f, 0.f, 0.f, 0.f};

    const int ch0 = tid, ch1 = tid + 256;
    const u16* ag0 = A + (size_t)(m0 + (ch0 >> 2)) * KPAD + (ch0 & 3) * 8;
    const u16* ag1 = A + (size_t)(m0 + (ch1 >> 2)) * KPAD + (ch1 & 3) * 8;
    const u16* bg0 = Bt + (size_t)(n0 + (ch0 >> 2)) * KPAD + (ch0 & 3) * 8;
    const u16* bg1 = Bt + (size_t)(n0 + (ch1 >> 2)) * KPAD + (ch1 & 3) * 8;
    u16* la0 = &As[ch0 * 8];
    u16* la1 = &As[ch1 * 8];
    u16* lb0 = &Bs[ch0 * 8];
    u16* lb1 = &Bs[ch1 * 8];

    for (int k0 = 0; k0 < KPAD; k0 += 32) {
        gl2lds16(ag0, la0);
        gl2lds16(ag1, la1);
        gl2lds16(bg0, lb0);
        gl2lds16(bg1, lb1);
        ag0 += 32; ag1 += 32; bg0 += 32; bg1 += 32;
        __syncthreads();

        bf16x8 af[4], bfr[4];
#pragma unroll
        for (int i = 0; i < 4; ++i)
            af[i] = *(const bf16x8*)&As[(wm + i * 16 + l16) * 32 + quad * 8];
#pragma unroll
        for (int j = 0; j < 4; ++j)
            bfr[j] = *(const bf16x8*)&Bs[(wn + j * 16 + l16) * 32 + quad * 8];
#pragma unroll
        for (int i = 0; i < 4; ++i)
#pragma unroll
            for (int j = 0; j < 4; ++j)
                acc[i][j] = __builtin_amdgcn_mfma_f32_16x16x32_bf16(af[i], bfr[j], acc[i][j], 0, 0, 0);
        __syncthreads();
    }

#pragma unroll
    for (int j = 0; j < 4; ++j) {
        const int col = n0 + wn + j * 16 + l16;
        const float bv = b1[col];
#pragma unroll
        for (int i = 0; i < 4; ++i) {
            const int rbase = m0 + wm + i * 16 + quad * 4;
#pragma unroll
            for (int r = 0; r < 4; ++r) {
                float v = acc[i][j][r] + bv;
                v = v > 0.f ? v : 0.f;
                H[(size_t)(rbase + r) * H1DIM + col] = f2b(v);
            }
        }
    }
}

// ---------------------------------------------------------------------------
// GEMM2: out[8192][100] += H[8192][2048] @ W2T^T + b2, split-K with atomics.
// ---------------------------------------------------------------------------
__global__ __launch_bounds__(256) void gemm2_kernel(const u16* __restrict__ Hh,
                                                    const u16* __restrict__ W2T,
                                                    const float* __restrict__ b2,
                                                    float* __restrict__ out) {
    __shared__ u16 As[64 * 32];
    __shared__ u16 Bs[NOUTP * 32];
    const int tid = threadIdx.x;
    const int m0 = blockIdx.y * 64;
    const int kc = blockIdx.x;
    const int kbase = kc * (H1DIM / KSPLIT);
    const int wave = tid >> 6;
    const int lane = tid & 63;
    const int quad = lane >> 4;
    const int l16 = lane & 15;

    f32x4 acc[7];
#pragma unroll
    for (int j = 0; j < 7; ++j) acc[j] = (f32x4){0.f, 0.f, 0.f, 0.f};

    const u16* ag = Hh + (size_t)(m0 + (tid >> 2)) * H1DIM + kbase + (tid & 3) * 8;
    u16* la = &As[tid * 8];
    const u16* bg0 = W2T + (size_t)(tid >> 2) * H1DIM + kbase + (tid & 3) * 8;
    u16* lb0 = &Bs[tid * 8];
    const int ch1 = tid + 256;
    const u16* bg1 = W2T + (size_t)(ch1 >> 2) * H1DIM + kbase + (ch1 & 3) * 8;
    u16* lb1 = &Bs[ch1 * 8];
    const bool bact = (ch1 < NOUTP * 4);

    for (int kk = 0; kk < H1DIM / KSPLIT; kk += 32) {
        gl2lds16(ag, la);
        gl2lds16(bg0, lb0);
        if (bact) gl2lds16(bg1, lb1);
        ag += 32; bg0 += 32; bg1 += 32;
        __syncthreads();

        bf16x8 af = *(const bf16x8*)&As[(wave * 16 + l16) * 32 + quad * 8];
#pragma unroll
        for (int j = 0; j < 7; ++j) {
            bf16x8 bfr = *(const bf16x8*)&Bs[(j * 16 + l16) * 32 + quad * 8];
            acc[j] = __builtin_amdgcn_mfma_f32_16x16x32_bf16(af, bfr, acc[j], 0, 0, 0);
        }
        __syncthreads();
    }

#pragma unroll
    for (int j = 0; j < 7; ++j) {
        const int col = j * 16 + l16;
        if (col < NOUT) {
            const float bv = (kc == 0) ? b2[col] : 0.f;
            const int rbase = m0 + wave * 16 + quad * 4;
#pragma unroll
            for (int r = 0; r < 4; ++r)
                atomicAdd(&out[(size_t)(rbase + r) * NOUT + col], acc[j][r] + bv);
        }
    }
}

// ---------------------------------------------------------------------------
extern "C" void kernel_launch(void* const* d_in, const int* in_sizes, int n_in,
                              void* d_out, int out_size, void* d_ws, size_t ws_size,
                              hipStream_t stream) {
    const float* inputs = (const float*)d_in[0];
    const void*  edges  = d_in[1];
    const float* gcn_w  = (const float*)d_in[2];
    const float* gcn_b  = (const float*)d_in[3];
    const float* W1     = (const float*)d_in[4];
    const float* b1     = (const float*)d_in[5];
    const float* W2     = (const float*)d_in[6];
    const float* b2     = (const float*)d_in[7];
    float* out = (float*)d_out;

    const int N = in_sizes[0];          // 8192 * 978 = 8,011,776
    const int Brows = N / NGENES;       // 8192
    const int E = in_sizes[1] / 2;      // 20,000,000

    char* ws = (char*)d_ws;
    size_t off = 0;
    auto carve = [&](size_t bytes) -> void* {
        void* p = ws + off;
        off = (off + bytes + 255) & ~(size_t)255;
        return p;
    };
    float* agg = (float*)carve((size_t)N * 4);
    u16*   Abf = (u16*)carve((size_t)Brows * KPAD * 2);
    u16*   W1T = (u16*)carve((size_t)H1DIM * KPAD * 2);
    u16*   W2Tp = (u16*)carve((size_t)NOUTP * H1DIM * 2);
    u16*   H1  = (u16*)carve((size_t)Brows * H1DIM * 2);
    int*   flag = (int*)carve(256);
    // binned-scatter extras
    u16*   xb     = (u16*)carve((size_t)N * 2);
    u32*   cnt    = (u32*)carve((size_t)(NB + 64) * 4);   // cnt[NB] + ovfcnt
    u32*   ovfcnt = cnt + NB;
    u32*   ovfg   = (u32*)carve((size_t)(1 << 20) * 8);   // spill list (8 MB)
    u32*   pairs  = (u32*)carve((size_t)NB * CAP_B * 4);  // 91.7 MB
    const bool use_binned = (off <= ws_size);

    hipMemsetAsync(out, 0, (size_t)out_size * 4, stream);
    detect_kernel<<<1, 64, 0, stream>>>((const unsigned*)edges, flag);

    if (use_binned) {
        hipMemsetAsync(cnt, 0, (size_t)(NB + 64) * 4, stream);
        xbf_kernel<<<(N / 4 + 255) / 256, 256, 0, stream>>>(inputs, gcn_w, xb, N);
        binscatter_kernel<<<SC_WGS, SC_THR, 0, stream>>>(edges, xb, flag, E,
                                                         pairs, cnt, ovfg, ovfcnt);
        accum_kernel<<<NB, 512, 0, stream>>>(pairs, cnt, agg);
        ovf_fix_kernel<<<8, 256, 0, stream>>>(ovfg, ovfcnt, agg);
    } else {
        hipMemsetAsync(agg, 0, (size_t)N * 4, stream);
        const int sblocks = (E + 255) / 256;
        scatter_kernel<<<sblocks, 256, 0, stream>>>(edges, inputs, gcn_w, agg, flag, E);
    }

    act_kernel<<<(Brows * KPAD) / 256, 256, 0, stream>>>(agg, gcn_b, Abf);

    transposeW1<<<dim3(H1DIM / 32, KPAD / 32), dim3(32, 8), 0, stream>>>(W1, W1T);
    transposeW2<<<dim3(4, H1DIM / 32), dim3(32, 8), 0, stream>>>(W2, W2Tp);

    gemm1_kernel<<<dim3(H1DIM / 128, Brows / 128), 256, 0, stream>>>(Abf, W1T, b1, H1);
    gemm2_kernel<<<dim3(KSPLIT, Brows / 64), 256, 0, stream>>>(H1, W2Tp, b2, out);
}